// Round 2
// baseline (1640.122 us; speedup 1.0000x reference)
//
#include <hip/hip_runtime.h>
#include <hip/hip_bf16.h>

typedef __bf16 bf16x8 __attribute__((ext_vector_type(8)));
typedef float f32x4 __attribute__((ext_vector_type(4)));
typedef unsigned short u16;
typedef u16 u16x4 __attribute__((ext_vector_type(4)));
typedef u16 u16x8 __attribute__((ext_vector_type(8)));

__device__ __forceinline__ u16 bfbits(float f) {
  return __builtin_bit_cast(u16, (__bf16)f);
}

// ---------------- prep: weights -> bf16, bias gather (transposed [h][key][query]) ----------------
__global__ void wattn_prep(const float* __restrict__ wq, const float* __restrict__ wp,
                           const float* __restrict__ rpb, const int* __restrict__ rpi,
                           u16* __restrict__ wqb, u16* __restrict__ wpb,
                           float* __restrict__ biasb) {
  int i = blockIdx.x * blockDim.x + threadIdx.x;      // 196608 threads
  if (i < 196608) wqb[i] = bfbits(wq[i]);             // w_qkv [768][256]
  if (i < 65536)  wpb[i] = bfbits(wp[i]);             // w_proj [256][256]
  if (i < 32768) {                                    // biasT [8][key 64][query 64]
    int h = i >> 12, nm = i & 4095;
    int k_ = nm >> 6, q = nm & 63;
    biasb[i] = rpb[rpi[q * 64 + k_] * 8 + h];
  }
}

// ---------------- fused window attention ----------------
// block = 1 window, 512 threads = 8 waves, wave w = head w
// LDS: Xb [64][264] bf16 (aliased as attn_out [64][264] later) | Vt 8 x [32][72] bf16
// Q,K,P never touch LDS: transposed QKV GEMM + k-permutation feeds MFMA fragments in-register.
__global__ __launch_bounds__(512, 4)
void wattn_main(const float* __restrict__ x,
                const u16* __restrict__ wq, const float* __restrict__ bq,
                const u16* __restrict__ wp, const float* __restrict__ bp,
                const float* __restrict__ biasT,
                float* __restrict__ out) {
  extern __shared__ u16 sm[];
  u16* Xb = sm;                       // 64*264 = 16896 u16
  u16* Vt = sm + 16896;               // 8 * 32*72 = 18432 u16

  const int b    = blockIdx.x;
  const int tid  = threadIdx.x;
  const int w    = tid >> 6;          // wave = head
  const int lane = tid & 63;
  const int g    = lane >> 4;
  const int li   = lane & 15;
  const int hc   = 32 * w;

  // ---- stage x -> bf16 LDS ----
  {
    const float4* xg = (const float4*)(x + (size_t)b * 16384);
    #pragma unroll
    for (int i = 0; i < 8; ++i) {
      int idx = tid + i * 512;        // 0..4095 float4s
      float4 v = xg[idx];
      int n = idx >> 6, c = (idx & 63) * 4;
      u16x4 h;
      h[0] = bfbits(v.x); h[1] = bfbits(v.y); h[2] = bfbits(v.z); h[3] = bfbits(v.w);
      *(u16x4*)(Xb + n * 264 + c) = h;
    }
  }
  __syncthreads();

  // ---- pass 1: Q^T, K^T = Wq|Wk · x^T   (M = d-channel, N = token, K = 256) ----
  f32x4 aq[2][4], ak[2][4];
  #pragma unroll
  for (int mt = 0; mt < 2; ++mt)
    #pragma unroll
    for (int nt = 0; nt < 4; ++nt) { aq[mt][nt] = f32x4{0,0,0,0}; ak[mt][nt] = f32x4{0,0,0,0}; }

  #pragma unroll
  for (int ks = 0; ks < 8; ++ks) {
    bf16x8 xb[4];
    #pragma unroll
    for (int nt = 0; nt < 4; ++nt)
      xb[nt] = *(const bf16x8*)(Xb + (16 * nt + li) * 264 + 32 * ks + 8 * g);
    #pragma unroll
    for (int mt = 0; mt < 2; ++mt) {
      bf16x8 wfq = *(const bf16x8*)(wq + (hc + 16 * mt + li) * 256 + 32 * ks + 8 * g);
      #pragma unroll
      for (int nt = 0; nt < 4; ++nt)
        aq[mt][nt] = __builtin_amdgcn_mfma_f32_16x16x32_bf16(wfq, xb[nt], aq[mt][nt], 0, 0, 0);
      bf16x8 wfk = *(const bf16x8*)(wq + (256 + hc + 16 * mt + li) * 256 + 32 * ks + 8 * g);
      #pragma unroll
      for (int nt = 0; nt < 4; ++nt)
        ak[mt][nt] = __builtin_amdgcn_mfma_f32_16x16x32_bf16(wfk, xb[nt], ak[mt][nt], 0, 0, 0);
    }
  }

  // convert C-fragments -> S-mfma operand fragments in-register.
  // k-slot permutation pi(g,j): j<4 -> d=4g+j ; j>=4 -> d=16+4g+(j-4). Consistent for A and B.
  const float scale = 0.17677669529663687f;   // 1/sqrt(32)
  float bQ[8], bK[8];
  #pragma unroll
  for (int j = 0; j < 8; ++j) {
    int d = (j < 4) ? (4 * g + j) : (16 + 4 * g + (j - 4));
    bQ[j] = bq[hc + d];
    bK[j] = bq[256 + hc + d];
  }
  bf16x8 qf[4], kf[4];
  #pragma unroll
  for (int t = 0; t < 4; ++t)
    #pragma unroll
    for (int j = 0; j < 8; ++j) {
      float qv = ((j < 4 ? aq[0][t][j] : aq[1][t][j - 4]) + bQ[j]) * scale;
      float kv =  (j < 4 ? ak[0][t][j] : ak[1][t][j - 4]) + bK[j];
      qf[t][j] = (__bf16)qv;
      kf[t][j] = (__bf16)kv;
    }

  // ---- pass 2: V^T = Wv · x^T ----
  f32x4 av[2][4];
  #pragma unroll
  for (int mt = 0; mt < 2; ++mt)
    #pragma unroll
    for (int nt = 0; nt < 4; ++nt) av[mt][nt] = f32x4{0,0,0,0};
  #pragma unroll
  for (int ks = 0; ks < 8; ++ks) {
    bf16x8 xb[4];
    #pragma unroll
    for (int nt = 0; nt < 4; ++nt)
      xb[nt] = *(const bf16x8*)(Xb + (16 * nt + li) * 264 + 32 * ks + 8 * g);
    #pragma unroll
    for (int mt = 0; mt < 2; ++mt) {
      bf16x8 wfv = *(const bf16x8*)(wq + (512 + hc + 16 * mt + li) * 256 + 32 * ks + 8 * g);
      #pragma unroll
      for (int nt = 0; nt < 4; ++nt)
        av[mt][nt] = __builtin_amdgcn_mfma_f32_16x16x32_bf16(wfv, xb[nt], av[mt][nt], 0, 0, 0);
    }
  }
  // write V^T to wave-private LDS: Vt[d][token], stride 72
  u16* VtW = Vt + w * 2304;
  #pragma unroll
  for (int mt = 0; mt < 2; ++mt)
    #pragma unroll
    for (int e = 0; e < 4; ++e) {
      float bb = bq[512 + hc + 16 * mt + 4 * g + e];
      #pragma unroll
      for (int nt = 0; nt < 4; ++nt)
        VtW[(16 * mt + 4 * g + e) * 72 + 16 * nt + li] = bfbits(av[mt][nt][e] + bb);
    }

  // ---- S^T = K·Q^T  (row = key, col = query), K-dim = 32 = full d ----
  f32x4 s[4][4];
  #pragma unroll
  for (int rt = 0; rt < 4; ++rt)
    #pragma unroll
    for (int ct = 0; ct < 4; ++ct)
      s[rt][ct] = __builtin_amdgcn_mfma_f32_16x16x32_bf16(kf[rt], qf[ct], f32x4{0,0,0,0}, 0, 0, 0);

  // ---- bias + softmax over keys (in-lane 16 + shfl_xor 16,32) ----
  {
    const float* bT = biasT + w * 4096;   // [key][query]
    #pragma unroll
    for (int ct = 0; ct < 4; ++ct) {
      float mx = -1e30f;
      #pragma unroll
      for (int rt = 0; rt < 4; ++rt)
        #pragma unroll
        for (int e = 0; e < 4; ++e) {
          s[rt][ct][e] += bT[(16 * rt + 4 * g + e) * 64 + 16 * ct + li];
          mx = fmaxf(mx, s[rt][ct][e]);
        }
      mx = fmaxf(mx, __shfl_xor(mx, 16));
      mx = fmaxf(mx, __shfl_xor(mx, 32));
      float sum = 0.f;
      #pragma unroll
      for (int rt = 0; rt < 4; ++rt)
        #pragma unroll
        for (int e = 0; e < 4; ++e) {
          float p = __expf(s[rt][ct][e] - mx);
          s[rt][ct][e] = p;
          sum += p;
        }
      sum += __shfl_xor(sum, 16);
      sum += __shfl_xor(sum, 32);
      float rs = 1.0f / sum;
      #pragma unroll
      for (int rt = 0; rt < 4; ++rt)
        #pragma unroll
        for (int e = 0; e < 4; ++e) s[rt][ct][e] *= rs;
    }
  }

  // ---- P fragments in-register (same k-permutation over keys) ----
  bf16x8 pa[4][2];
  #pragma unroll
  for (int ct = 0; ct < 4; ++ct)
    #pragma unroll
    for (int kk = 0; kk < 2; ++kk)
      #pragma unroll
      for (int j = 0; j < 8; ++j)
        pa[ct][kk][j] = (__bf16)(j < 4 ? s[2 * kk][ct][j] : s[2 * kk + 1][ct][j - 4]);

  // ---- O = P·V  (M = query, N = d, k = key via permuted Vt reads) ----
  f32x4 o[4][2];
  #pragma unroll
  for (int mt = 0; mt < 4; ++mt)
    #pragma unroll
    for (int nt = 0; nt < 2; ++nt) o[mt][nt] = f32x4{0,0,0,0};
  #pragma unroll
  for (int kk = 0; kk < 2; ++kk) {
    bf16x8 vb[2];
    #pragma unroll
    for (int nt = 0; nt < 2; ++nt) {
      const u16* row = VtW + (16 * nt + li) * 72;
      u16x4 lo = *(const u16x4*)(row + 32 * kk + 4 * g);
      u16x4 hi = *(const u16x4*)(row + 32 * kk + 16 + 4 * g);
      u16x8 cc;
      #pragma unroll
      for (int j = 0; j < 4; ++j) { cc[j] = lo[j]; cc[4 + j] = hi[j]; }
      vb[nt] = __builtin_bit_cast(bf16x8, cc);
    }
    #pragma unroll
    for (int mt = 0; mt < 4; ++mt)
      #pragma unroll
      for (int nt = 0; nt < 2; ++nt)
        o[mt][nt] = __builtin_amdgcn_mfma_f32_16x16x32_bf16(pa[mt][kk], vb[nt], o[mt][nt], 0, 0, 0);
  }

  // ---- attn_out -> LDS (aliases Xb; all Xb reads are done after pass 2) ----
  __syncthreads();
  u16* ao = sm;                       // [64][264]
  #pragma unroll
  for (int mt = 0; mt < 4; ++mt)
    #pragma unroll
    for (int nt = 0; nt < 2; ++nt)
      #pragma unroll
      for (int e = 0; e < 4; ++e)
        ao[(16 * mt + 4 * g + e) * 264 + hc + 16 * nt + li] = bfbits(o[mt][nt][e]);
  __syncthreads();

  // ---- proj: out = attn_out @ Wp^T + bp ; wave w -> cols 32w..32w+31 ----
  f32x4 c2[4][2];
  #pragma unroll
  for (int rt = 0; rt < 4; ++rt)
    #pragma unroll
    for (int ct = 0; ct < 2; ++ct) c2[rt][ct] = f32x4{0,0,0,0};
  #pragma unroll
  for (int ks = 0; ks < 8; ++ks) {
    bf16x8 af[4];
    #pragma unroll
    for (int rt = 0; rt < 4; ++rt)
      af[rt] = *(const bf16x8*)(ao + (16 * rt + li) * 264 + 32 * ks + 8 * g);
    bf16x8 wf[2];
    #pragma unroll
    for (int ct = 0; ct < 2; ++ct)
      wf[ct] = *(const bf16x8*)(wp + (32 * w + 16 * ct + li) * 256 + 32 * ks + 8 * g);
    #pragma unroll
    for (int rt = 0; rt < 4; ++rt)
      #pragma unroll
      for (int ct = 0; ct < 2; ++ct)
        c2[rt][ct] = __builtin_amdgcn_mfma_f32_16x16x32_bf16(af[rt], wf[ct], c2[rt][ct], 0, 0, 0);
  }
  {
    float* og = out + (size_t)b * 16384;
    #pragma unroll
    for (int ct = 0; ct < 2; ++ct) {
      int col = 32 * w + 16 * ct + li;
      float bpv = bp[col];
      #pragma unroll
      for (int rt = 0; rt < 4; ++rt)
        #pragma unroll
        for (int e = 0; e < 4; ++e)
          og[(16 * rt + 4 * g + e) * 256 + col] = c2[rt][ct][e] + bpv;
    }
  }
}

extern "C" void kernel_launch(void* const* d_in, const int* in_sizes, int n_in,
                              void* d_out, int out_size, void* d_ws, size_t ws_size,
                              hipStream_t stream) {
  const float* x   = (const float*)d_in[0];
  const float* wqv = (const float*)d_in[1];
  const float* bq  = (const float*)d_in[2];
  const float* wpr = (const float*)d_in[3];
  const float* bp  = (const float*)d_in[4];
  const float* rpb = (const float*)d_in[5];
  const int*   rpi = (const int*)d_in[6];
  float* out = (float*)d_out;

  u16*   wqb   = (u16*)d_ws;            // 196608 bf16
  u16*   wpb   = wqb + 196608;          // 65536 bf16
  float* biasb = (float*)(wpb + 65536); // 32768 f32 (transposed [h][key][query])

  wattn_prep<<<384, 512, 0, stream>>>(wqv, wpr, rpb, rpi, wqb, wpb, biasb);

  const size_t smem = (16896 + 18432) * sizeof(u16);  // 70656 B -> 2 blocks/CU
  hipFuncSetAttribute(reinterpret_cast<const void*>(wattn_main),
                      hipFuncAttributeMaxDynamicSharedMemorySize, (int)smem);
  wattn_main<<<8192, 512, smem, stream>>>(x, wqb, bq, wpb, bp, biasb, out);
}

// Round 3
// 704.079 us; speedup vs baseline: 2.3295x; 2.3295x over previous
//
#include <hip/hip_runtime.h>
#include <hip/hip_bf16.h>

typedef __bf16 bf16x8 __attribute__((ext_vector_type(8)));
typedef float f32x4 __attribute__((ext_vector_type(4)));
typedef unsigned short u16;
typedef u16 u16x4 __attribute__((ext_vector_type(4)));
typedef u16 u16x8 __attribute__((ext_vector_type(8)));

__device__ __forceinline__ u16 bfbits(float f) {
  return __builtin_bit_cast(u16, (__bf16)f);
}

// ---------------- prep: weights -> bf16, bias gather [h][query][key] ----------------
__global__ void wattn_prep(const float* __restrict__ wq, const float* __restrict__ wp,
                           const float* __restrict__ rpb, const int* __restrict__ rpi,
                           u16* __restrict__ wqb, u16* __restrict__ wpb,
                           float* __restrict__ biasb) {
  int i = blockIdx.x * blockDim.x + threadIdx.x;      // 196608 threads
  if (i < 196608) wqb[i] = bfbits(wq[i]);             // w_qkv [768][256]
  if (i < 65536)  wpb[i] = bfbits(wp[i]);             // w_proj [256][256]
  if (i < 32768) {                                    // bias [8][query 64][key 64]
    int h = i >> 12, nm = i & 4095;
    biasb[i] = rpb[rpi[nm] * 8 + h];
  }
}

// ---------------- fused window attention ----------------
// block = 1 window, 512 threads = 8 waves, wave w = head w
// LDS: Xb [64][264] bf16 (later aliased as attn_out) | Vt 8 x [32][72] bf16
// Q,K,P stay in registers (transposed QKV GEMM + k-slot permutation).
// Register discipline: V sweep -> Q sweep -> K sweep (never two accumulator sets live),
// per-ct softmax (s4[4] only), unroll-2 weight streams, sched_barrier between phases.
__global__ __launch_bounds__(512, 4)
void wattn_main(const float* __restrict__ x,
                const u16* __restrict__ wq, const float* __restrict__ bq,
                const u16* __restrict__ wp, const float* __restrict__ bp,
                const float* __restrict__ bias,
                float* __restrict__ out) {
  extern __shared__ u16 sm[];
  u16* Xb = sm;                       // 64*264 = 16896 u16
  u16* Vt = sm + 16896;               // 8 * 32*72 = 18432 u16

  const int b    = blockIdx.x;
  const int tid  = threadIdx.x;
  const int w    = tid >> 6;          // wave = head
  const int lane = tid & 63;
  const int g    = lane >> 4;
  const int li   = lane & 15;
  const int hc   = 32 * w;

  // ---- stage x -> bf16 LDS ----
  {
    const float4* xg = (const float4*)(x + (size_t)b * 16384);
    #pragma unroll
    for (int i = 0; i < 8; ++i) {
      int idx = tid + i * 512;
      float4 v = xg[idx];
      int n = idx >> 6, c = (idx & 63) * 4;
      u16x4 h;
      h[0] = bfbits(v.x); h[1] = bfbits(v.y); h[2] = bfbits(v.z); h[3] = bfbits(v.w);
      *(u16x4*)(Xb + n * 264 + c) = h;
    }
  }
  __syncthreads();

  const int xoff = li * 264 + 8 * g;        // per-lane Xb fragment base

  // ======== V sweep: V^T = Wv . x^T ========
  f32x4 av[2][4];
  #pragma unroll
  for (int mt = 0; mt < 2; ++mt)
    #pragma unroll
    for (int nt = 0; nt < 4; ++nt) av[mt][nt] = f32x4{0,0,0,0};
  #pragma unroll 2
  for (int ks = 0; ks < 8; ++ks) {
    bf16x8 xb[4];
    #pragma unroll
    for (int nt = 0; nt < 4; ++nt)
      xb[nt] = *(const bf16x8*)(Xb + xoff + nt * (16 * 264) + 32 * ks);
    #pragma unroll
    for (int mt = 0; mt < 2; ++mt) {
      bf16x8 wf = *(const bf16x8*)(wq + (512 + hc + 16 * mt + li) * 256 + 32 * ks + 8 * g);
      #pragma unroll
      for (int nt = 0; nt < 4; ++nt)
        av[mt][nt] = __builtin_amdgcn_mfma_f32_16x16x32_bf16(wf, xb[nt], av[mt][nt], 0, 0, 0);
    }
  }
  {
    u16* VtW = Vt + w * 2304;               // wave-private [32 d][72]
    #pragma unroll
    for (int mt = 0; mt < 2; ++mt)
      #pragma unroll
      for (int e = 0; e < 4; ++e) {
        float bb = bq[512 + hc + 16 * mt + 4 * g + e];
        #pragma unroll
        for (int nt = 0; nt < 4; ++nt)
          VtW[(16 * mt + 4 * g + e) * 72 + 16 * nt + li] = bfbits(av[mt][nt][e] + bb);
      }
  }
  __builtin_amdgcn_sched_barrier(0);

  // ======== Q sweep: Q^T = Wq . x^T -> qf fragments ========
  const float scale = 0.17677669529663687f;   // 1/sqrt(32)
  bf16x8 qf[4];
  {
    f32x4 aq[2][4];
    #pragma unroll
    for (int mt = 0; mt < 2; ++mt)
      #pragma unroll
      for (int nt = 0; nt < 4; ++nt) aq[mt][nt] = f32x4{0,0,0,0};
    #pragma unroll 2
    for (int ks = 0; ks < 8; ++ks) {
      bf16x8 xb[4];
      #pragma unroll
      for (int nt = 0; nt < 4; ++nt)
        xb[nt] = *(const bf16x8*)(Xb + xoff + nt * (16 * 264) + 32 * ks);
      #pragma unroll
      for (int mt = 0; mt < 2; ++mt) {
        bf16x8 wf = *(const bf16x8*)(wq + (hc + 16 * mt + li) * 256 + 32 * ks + 8 * g);
        #pragma unroll
        for (int nt = 0; nt < 4; ++nt)
          aq[mt][nt] = __builtin_amdgcn_mfma_f32_16x16x32_bf16(wf, xb[nt], aq[mt][nt], 0, 0, 0);
      }
    }
    // k-slot permutation pi(g,j): j<4 -> d=4g+j ; j>=4 -> d=16+4g+(j-4)
    #pragma unroll
    for (int j = 0; j < 8; ++j) {
      int d = (j < 4) ? (4 * g + j) : (16 + 4 * g + (j - 4));
      float bb = bq[hc + d];
      #pragma unroll
      for (int t = 0; t < 4; ++t)
        qf[t][j] = (__bf16)(((j < 4 ? aq[0][t][j] : aq[1][t][j - 4]) + bb) * scale);
    }
  }
  __builtin_amdgcn_sched_barrier(0);

  // ======== K sweep: K^T = Wk . x^T -> kf fragments ========
  bf16x8 kf[4];
  {
    f32x4 ak[2][4];
    #pragma unroll
    for (int mt = 0; mt < 2; ++mt)
      #pragma unroll
      for (int nt = 0; nt < 4; ++nt) ak[mt][nt] = f32x4{0,0,0,0};
    #pragma unroll 2
    for (int ks = 0; ks < 8; ++ks) {
      bf16x8 xb[4];
      #pragma unroll
      for (int nt = 0; nt < 4; ++nt)
        xb[nt] = *(const bf16x8*)(Xb + xoff + nt * (16 * 264) + 32 * ks);
      #pragma unroll
      for (int mt = 0; mt < 2; ++mt) {
        bf16x8 wf = *(const bf16x8*)(wq + (256 + hc + 16 * mt + li) * 256 + 32 * ks + 8 * g);
        #pragma unroll
        for (int nt = 0; nt < 4; ++nt)
          ak[mt][nt] = __builtin_amdgcn_mfma_f32_16x16x32_bf16(wf, xb[nt], ak[mt][nt], 0, 0, 0);
      }
    }
    #pragma unroll
    for (int j = 0; j < 8; ++j) {
      int d = (j < 4) ? (4 * g + j) : (16 + 4 * g + (j - 4));
      float bb = bq[256 + hc + d];
      #pragma unroll
      for (int t = 0; t < 4; ++t)
        kf[t][j] = (__bf16)((j < 4 ? ak[0][t][j] : ak[1][t][j - 4]) + bb);
    }
  }
  __builtin_amdgcn_sched_barrier(0);

  // ======== S^T = K.Q^T per query-tile; bias + softmax over keys; P fragments ========
  bf16x8 pa[4][2];
  {
    const float* bh = bias + w * 4096;      // [query][key]
    #pragma unroll
    for (int ct = 0; ct < 4; ++ct) {
      f32x4 s4[4];
      #pragma unroll
      for (int rt = 0; rt < 4; ++rt)
        s4[rt] = __builtin_amdgcn_mfma_f32_16x16x32_bf16(kf[rt], qf[ct], f32x4{0,0,0,0}, 0, 0, 0);
      const float* bq_row = bh + (16 * ct + li) * 64 + 4 * g;
      float mx = -1e30f;
      #pragma unroll
      for (int rt = 0; rt < 4; ++rt) {
        f32x4 bv = *(const f32x4*)(bq_row + 16 * rt);
        #pragma unroll
        for (int e = 0; e < 4; ++e) {
          s4[rt][e] += bv[e];
          mx = fmaxf(mx, s4[rt][e]);
        }
      }
      mx = fmaxf(mx, __shfl_xor(mx, 16));
      mx = fmaxf(mx, __shfl_xor(mx, 32));
      float sum = 0.f;
      #pragma unroll
      for (int rt = 0; rt < 4; ++rt)
        #pragma unroll
        for (int e = 0; e < 4; ++e) {
          float p = __expf(s4[rt][e] - mx);
          s4[rt][e] = p;
          sum += p;
        }
      sum += __shfl_xor(sum, 16);
      sum += __shfl_xor(sum, 32);
      float rs = 1.0f / sum;
      #pragma unroll
      for (int kk = 0; kk < 2; ++kk)
        #pragma unroll
        for (int j = 0; j < 8; ++j)
          pa[ct][kk][j] = (__bf16)((j < 4 ? s4[2 * kk][j] : s4[2 * kk + 1][j - 4]) * rs);
      __builtin_amdgcn_sched_barrier(0);
    }
  }

  // ======== O = P.V (keys via permuted Vt reads) ========
  f32x4 o[4][2];
  #pragma unroll
  for (int mt = 0; mt < 4; ++mt)
    #pragma unroll
    for (int nt = 0; nt < 2; ++nt) o[mt][nt] = f32x4{0,0,0,0};
  {
    const u16* VtW = Vt + w * 2304;
    #pragma unroll
    for (int kk = 0; kk < 2; ++kk) {
      bf16x8 vb[2];
      #pragma unroll
      for (int nt = 0; nt < 2; ++nt) {
        const u16* row = VtW + (16 * nt + li) * 72;
        u16x4 lo = *(const u16x4*)(row + 32 * kk + 4 * g);
        u16x4 hi = *(const u16x4*)(row + 32 * kk + 16 + 4 * g);
        u16x8 cc;
        #pragma unroll
        for (int j = 0; j < 4; ++j) { cc[j] = lo[j]; cc[4 + j] = hi[j]; }
        vb[nt] = __builtin_bit_cast(bf16x8, cc);
      }
      #pragma unroll
      for (int mt = 0; mt < 4; ++mt)
        #pragma unroll
        for (int nt = 0; nt < 2; ++nt)
          o[mt][nt] = __builtin_amdgcn_mfma_f32_16x16x32_bf16(pa[mt][kk], vb[nt], o[mt][nt], 0, 0, 0);
    }
  }

  // ======== attn_out -> LDS (aliases Xb) ========
  __syncthreads();
  u16* ao = sm;                       // [64][264]
  #pragma unroll
  for (int mt = 0; mt < 4; ++mt)
    #pragma unroll
    for (int nt = 0; nt < 2; ++nt)
      #pragma unroll
      for (int e = 0; e < 4; ++e)
        ao[(16 * mt + 4 * g + e) * 264 + hc + 16 * nt + li] = bfbits(o[mt][nt][e]);
  __syncthreads();

  // ======== proj: out = attn_out @ Wp^T + bp ========
  f32x4 c2[4][2];
  #pragma unroll
  for (int rt = 0; rt < 4; ++rt)
    #pragma unroll
    for (int ct = 0; ct < 2; ++ct) c2[rt][ct] = f32x4{0,0,0,0};
  #pragma unroll 2
  for (int ks = 0; ks < 8; ++ks) {
    bf16x8 af[4];
    #pragma unroll
    for (int rt = 0; rt < 4; ++rt)
      af[rt] = *(const bf16x8*)(ao + xoff + rt * (16 * 264) + 32 * ks);
    bf16x8 wf[2];
    #pragma unroll
    for (int ct = 0; ct < 2; ++ct)
      wf[ct] = *(const bf16x8*)(wp + (32 * w + 16 * ct + li) * 256 + 32 * ks + 8 * g);
    #pragma unroll
    for (int rt = 0; rt < 4; ++rt)
      #pragma unroll
      for (int ct = 0; ct < 2; ++ct)
        c2[rt][ct] = __builtin_amdgcn_mfma_f32_16x16x32_bf16(af[rt], wf[ct], c2[rt][ct], 0, 0, 0);
  }
  {
    float* og = out + (size_t)b * 16384;
    #pragma unroll
    for (int ct = 0; ct < 2; ++ct) {
      int col = 32 * w + 16 * ct + li;
      float bpv = bp[col];
      #pragma unroll
      for (int rt = 0; rt < 4; ++rt)
        #pragma unroll
        for (int e = 0; e < 4; ++e)
          og[(16 * rt + 4 * g + e) * 256 + col] = c2[rt][ct][e] + bpv;
    }
  }
}

extern "C" void kernel_launch(void* const* d_in, const int* in_sizes, int n_in,
                              void* d_out, int out_size, void* d_ws, size_t ws_size,
                              hipStream_t stream) {
  const float* x   = (const float*)d_in[0];
  const float* wqv = (const float*)d_in[1];
  const float* bq  = (const float*)d_in[2];
  const float* wpr = (const float*)d_in[3];
  const float* bp  = (const float*)d_in[4];
  const float* rpb = (const float*)d_in[5];
  const int*   rpi = (const int*)d_in[6];
  float* out = (float*)d_out;

  u16*   wqb   = (u16*)d_ws;            // 196608 bf16
  u16*   wpb   = wqb + 196608;          // 65536 bf16
  float* biasb = (float*)(wpb + 65536); // 32768 f32 ([h][query][key])

  wattn_prep<<<384, 512, 0, stream>>>(wqv, wpr, rpb, rpi, wqb, wpb, biasb);

  const size_t smem = (16896 + 18432) * sizeof(u16);  // 70656 B -> 2 blocks/CU
  hipFuncSetAttribute(reinterpret_cast<const void*>(wattn_main),
                      hipFuncAttributeMaxDynamicSharedMemorySize, (int)smem);
  wattn_main<<<8192, 512, smem, stream>>>(x, wqb, bq, wpb, bp, biasb, out);
}